// Round 1
// baseline (905.192 us; speedup 1.0000x reference)
//
#include <hip/hip_runtime.h>
#include <hip/hip_bf16.h>

#define NB 8192
#define NN 128
#define DD 64
#define NE 100000

typedef __bf16 bf16x8 __attribute__((ext_vector_type(8)));
typedef float  f32x4  __attribute__((ext_vector_type(4)));

// ---- cross-lane reductions ------------------------------------------------
template<int C>
__device__ __forceinline__ float dpp_mov(float v) {
  return __int_as_float(__builtin_amdgcn_update_dpp(
      0, __float_as_int(v), C, 0xF, 0xF, true));
}

// sum across all 64 lanes, result in all lanes.
// DPP for xor1/2/4/8 (VALU pipe), ds_swizzle for xor16, shfl for xor32.
__device__ __forceinline__ float red64(float v) {
  v += dpp_mov<0xB1>(v);   // quad_perm [1,0,3,2]  == xor 1
  v += dpp_mov<0x4E>(v);   // quad_perm [2,3,0,1]  == xor 2
  v += dpp_mov<0x141>(v);  // row_half_mirror      == xor 4 (after quads summed)
  v += dpp_mov<0x140>(v);  // row_mirror           == xor 8 (after 8-groups summed)
  v += __int_as_float(__builtin_amdgcn_ds_swizzle(__float_as_int(v), 0x401F)); // xor 16
  v += __shfl_xor(v, 32, 64);                                                 // xor 32
  return v;
}

// sum across each 16-lane group (DPP only, VALU pipe)
__device__ __forceinline__ float red16(float v) {
  v += dpp_mov<0xB1>(v);
  v += dpp_mov<0x4E>(v);
  v += dpp_mov<0x141>(v);
  v += dpp_mov<0x140>(v);
  return v;
}

// overflow-free tanh: (1-e)/(1+e), e = exp(-2|x|) in (0,1]
__device__ __forceinline__ float fast_tanh(float x) {
  float e = __expf(-2.0f * fabsf(x));
  float t = (1.0f - e) * __builtin_amdgcn_rcpf(1.0f + e);
  return copysignf(t, x);
}

// ---- prep: pack W2 (= att_w rows 64..127) into MFMA B-fragment layout, and
// precompute qpart[rid][j] = sum_k qrel[rid][k] * att_w[k][j] for all 1000 rids.
__global__ void prep_kernel(const float* __restrict__ att_w,
                            const float* __restrict__ qrel,
                            __bf16* __restrict__ wsf,      // 8*2*64*8 bf16 = 16 KB
                            float*  __restrict__ qpart) {  // 1000*128 f32
  const int t = threadIdx.x;      // 128 threads
  const int bid = blockIdx.x;
  if (bid == 0) {
    // B frag (tc,ks): lane l, elem e -> W2[k][j], k = ks*32 + (l>>4)*8 + e,
    // j = tc*16 + (l&15); W2[k][j] = att_w[(64+k)*128 + j]
    for (int i = t; i < 8192; i += 128) {
      int e  = i & 7;
      int l  = (i >> 3) & 63;
      int ks = (i >> 9) & 1;
      int tc = i >> 10;
      int k = ks * 32 + ((l >> 4) << 3) + e;
      int j = tc * 16 + (l & 15);
      wsf[i] = (__bf16)att_w[(64 + k) * 128 + j];
    }
  } else {
    int rid = bid - 1;            // 0..999
    float acc = 0.f;
    for (int k = 0; k < 64; ++k)
      acc += qrel[rid * 64 + k] * att_w[k * 128 + t];
    qpart[rid * 128 + t] = acc;
  }
}

// ---- main: one block per batch row b ------------------------------------
__global__ __launch_bounds__(256, 2)
void attn_kernel(const float* __restrict__ inp,
                 const int*   __restrict__ nb,
                 const int*   __restrict__ qid_p,
                 const float* __restrict__ wgt,
                 const float* __restrict__ mlp,
                 const float* __restrict__ attv,
                 const __bf16* __restrict__ wsf,
                 const float* __restrict__ qpart_t,
                 float* __restrict__ out) {
  __shared__ __attribute__((aligned(16))) float  T32[128][65];  // transformed, fp32
  __shared__ __attribute__((aligned(16))) __bf16 T16[128][72];  // transformed, bf16 (MFMA A)
  __shared__ float qp[128], plog[128], mlog[128], awl[128], wrat[128];
  __shared__ float part[4][64];

  const int t    = threadIdx.x;
  const int lane = t & 63;
  const int w    = t >> 6;       // wave id 0..3
  const int b    = blockIdx.x;

  if (t < 128) {
    int qid = qid_p[b];
    qp[t] = qpart_t[qid * 128 + t];
    float w0 = wgt[((size_t)b * 128 + t) * 2 + 0];
    float w1 = wgt[((size_t)b * 128 + t) * 2 + 1];
    wrat[t] = w0 / (w1 + 1.0f);
  }

  // ---- phase A: per-row projection; lane = embedding dim ----
  {
    const int kk = lane;
    const size_t inbase = ((size_t)b * 128 + w * 32) * 64 + kk;
    const int    nbbase = (b * 128 + w * 32) * 2;
#pragma unroll 4
    for (int i = 0; i < 32; ++i) {
      int n   = w * 32 + i;
      int rel = nb[nbbase + i * 2 + 0];
      int ent = nb[nbbase + i * 2 + 1];
      float rv = mlp[(size_t)rel * 64 + kk];
      float iv = inp[inbase + (size_t)i * 64];
      float s1 = red64(rv * rv);   // ||r||^2
      float s2 = red64(iv * rv);   // in . r
      // t = in - (in.r / max(||r||,1e-12)^2) r   (== reference exactly)
      float f  = s2 / fmaxf(s1, 1e-24f);
      float tk = iv - f * rv;
      if (ent >= NE) tk = 0.0f;    // entity == NUM_ENTITY -> masked row
      T32[n][kk] = tk;
      T16[n][kk] = (__bf16)tk;
      if (kk == 0) mlog[n] = (ent == NE) ? 1e19f : 0.0f;
    }
  }
  __syncthreads();

  // ---- load B fragments (pre-packed, coalesced) + v ----
  bf16x8 bfr[8][2];
#pragma unroll
  for (int tc = 0; tc < 8; ++tc)
#pragma unroll
    for (int ks = 0; ks < 2; ++ks)
      bfr[tc][ks] = *reinterpret_cast<const bf16x8*>(wsf + ((tc * 2 + ks) * 64 + lane) * 8);
  float vv[8];
#pragma unroll
  for (int tc = 0; tc < 8; ++tc) vv[tc] = attv[tc * 16 + (lane & 15)];

  // ---- phase B: C = T @ W2 (+qpart), per wave rows [32w, 32w+32) ----
  f32x4 acc[2][8];
#pragma unroll
  for (int tc = 0; tc < 8; ++tc) {
    float q = qp[tc * 16 + (lane & 15)];   // col j = lane&15 + 16*tc for all 4 regs
    f32x4 qv = {q, q, q, q};
    acc[0][tc] = qv;
    acc[1][tc] = qv;
  }
  const int ar = lane & 15;
  const int kc = (lane >> 4) * 8;
  bf16x8 af[2][2];
#pragma unroll
  for (int tr = 0; tr < 2; ++tr) {
    int row = w * 32 + tr * 16 + ar;
    af[tr][0] = *reinterpret_cast<const bf16x8*>(&T16[row][kc]);
    af[tr][1] = *reinterpret_cast<const bf16x8*>(&T16[row][kc + 32]);
  }
#pragma unroll
  for (int tr = 0; tr < 2; ++tr)
#pragma unroll
    for (int tc = 0; tc < 8; ++tc) {
      acc[tr][tc] = __builtin_amdgcn_mfma_f32_16x16x32_bf16(af[tr][0], bfr[tc][0], acc[tr][tc], 0, 0, 0);
      acc[tr][tc] = __builtin_amdgcn_mfma_f32_16x16x32_bf16(af[tr][1], bfr[tc][1], acc[tr][tc], 0, 0, 0);
    }

  // ---- epilogue: logit_n = sum_j tanh(C[n][j]) * v[j] ----
#pragma unroll
  for (int tr = 0; tr < 2; ++tr) {
    float p0 = 0.f, p1 = 0.f, p2 = 0.f, p3 = 0.f;
#pragma unroll
    for (int tc = 0; tc < 8; ++tc) {
      p0 += fast_tanh(acc[tr][tc][0]) * vv[tc];
      p1 += fast_tanh(acc[tr][tc][1]) * vv[tc];
      p2 += fast_tanh(acc[tr][tc][2]) * vv[tc];
      p3 += fast_tanh(acc[tr][tc][3]) * vv[tc];
    }
    p0 = red16(p0); p1 = red16(p1); p2 = red16(p2); p3 = red16(p3);
    if ((lane & 15) == 0) {
      int row = w * 32 + tr * 16 + (lane >> 4) * 4;  // D layout: row=(lane>>4)*4+reg
      plog[row + 0] = p0;
      plog[row + 1] = p1;
      plog[row + 2] = p2;
      plog[row + 3] = p3;
    }
  }
  __syncthreads();

  // ---- softmax over n (wave 0), + weight ratio, write attention_weight ----
  if (w == 0) {
    float l0 = plog[lane]      - mlog[lane];
    float l1 = plog[lane + 64] - mlog[lane + 64];
    float m = fmaxf(l0, l1);
    m = fmaxf(m, __shfl_xor(m, 1, 64));
    m = fmaxf(m, __shfl_xor(m, 2, 64));
    m = fmaxf(m, __shfl_xor(m, 4, 64));
    m = fmaxf(m, __shfl_xor(m, 8, 64));
    m = fmaxf(m, __shfl_xor(m, 16, 64));
    m = fmaxf(m, __shfl_xor(m, 32, 64));
    float e0 = __expf(l0 - m), e1 = __expf(l1 - m);
    float s = e0 + e1;
    s += __shfl_xor(s, 1, 64);
    s += __shfl_xor(s, 2, 64);
    s += __shfl_xor(s, 4, 64);
    s += __shfl_xor(s, 8, 64);
    s += __shfl_xor(s, 16, 64);
    s += __shfl_xor(s, 32, 64);
    float inv = 1.0f / s;
    float a0 = e0 * inv + wrat[lane];
    float a1 = e1 * inv + wrat[lane + 64];
    awl[lane] = a0; awl[lane + 64] = a1;
    float* awout = out + (size_t)NB * 64;          // second output, flat-concat
    awout[(size_t)b * 128 + lane]      = a0;
    awout[(size_t)b * 128 + lane + 64] = a1;
  }
  __syncthreads();

  // ---- phase C: output[d] = sum_n T[n][d] * aw[n] ----
  {
    float s = 0.f;
#pragma unroll 8
    for (int i = 0; i < 32; ++i) {
      int n = w * 32 + i;
      s += T32[n][lane] * awl[n];
    }
    part[w][lane] = s;
  }
  __syncthreads();
  if (t < 64)
    out[(size_t)b * 64 + t] = part[0][t] + part[1][t] + part[2][t] + part[3][t];
}

// ---- host ----------------------------------------------------------------
extern "C" void kernel_launch(void* const* d_in, const int* in_sizes, int n_in,
                              void* d_out, int out_size, void* d_ws, size_t ws_size,
                              hipStream_t stream) {
  const float* inp  = (const float*)d_in[0];
  const int*   nb   = (const int*)d_in[1];   // neighbor (int32 per harness convention)
  const int*   qid  = (const int*)d_in[2];
  const float* wgt  = (const float*)d_in[3];
  const float* mlp  = (const float*)d_in[4];
  const float* qrel = (const float*)d_in[5];
  const float* attw = (const float*)d_in[6];
  const float* attv = (const float*)d_in[7];
  float* out = (float*)d_out;

  // ws layout: [0,16384) bf16 B-fragments; [16384, 16384+512000) qpart f32
  __bf16* wsf   = (__bf16*)d_ws;
  float*  qpart = (float*)((char*)d_ws + 16384);

  prep_kernel<<<1001, 128, 0, stream>>>(attw, qrel, wsf, qpart);
  attn_kernel<<<NB, 256, 0, stream>>>(inp, nb, qid, wgt, mlp, attv, wsf, qpart, out);
}

// Round 3
// 483.846 us; speedup vs baseline: 1.8708x; 1.8708x over previous
//
#include <hip/hip_runtime.h>
#include <hip/hip_bf16.h>

#define NB 8192
#define NE 100000

typedef __bf16 bf16x8 __attribute__((ext_vector_type(8)));
typedef __bf16 bf16x4 __attribute__((ext_vector_type(4)));
typedef float  f32x4  __attribute__((ext_vector_type(4)));

// ---- cross-lane reductions ------------------------------------------------
template<int C>
__device__ __forceinline__ float dpp_mov(float v) {
  return __int_as_float(__builtin_amdgcn_update_dpp(
      0, __float_as_int(v), C, 0xF, 0xF, true));
}

// sum across each 16-lane group (DPP only, VALU pipe, no lgkm waits)
__device__ __forceinline__ float red16(float v) {
  v += dpp_mov<0xB1>(v);   // xor 1 (quad_perm)
  v += dpp_mov<0x4E>(v);   // xor 2 (quad_perm)
  v += dpp_mov<0x141>(v);  // row_half_mirror -> sum over 8
  v += dpp_mov<0x140>(v);  // row_mirror      -> sum over 16
  return v;
}

// overflow-free tanh: (1-e)/(1+e), e = exp(-2|x|) in (0,1]
__device__ __forceinline__ float fast_tanh(float x) {
  float e = __expf(-2.0f * fabsf(x));
  float t = (1.0f - e) * __builtin_amdgcn_rcpf(1.0f + e);
  return copysignf(t, x);
}

// ---- prep: pack W2 (= att_w rows 64..127) into MFMA B-fragment layout, and
// precompute qpart[rid][j] = sum_k qrel[rid][k] * att_w[k][j] for all 1000 rids.
__global__ void prep_kernel(const float* __restrict__ att_w,
                            const float* __restrict__ qrel,
                            __bf16* __restrict__ wsf,      // 8*2*64*8 bf16 = 16 KB
                            float*  __restrict__ qpart) {  // 1000*128 f32
  const int t = threadIdx.x;      // 128 threads
  const int bid = blockIdx.x;
  if (bid == 0) {
    // B frag (tc,ks): lane l, elem e -> W2[k][j], k = ks*32 + (l>>4)*8 + e,
    // j = tc*16 + (l&15); W2[k][j] = att_w[(64+k)*128 + j]
    for (int i = t; i < 8192; i += 128) {
      int e  = i & 7;
      int l  = (i >> 3) & 63;
      int ks = (i >> 9) & 1;
      int tc = i >> 10;
      int k = ks * 32 + ((l >> 4) << 3) + e;
      int j = tc * 16 + (l & 15);
      wsf[i] = (__bf16)att_w[(64 + k) * 128 + j];
    }
  } else {
    int rid = bid - 1;            // 0..999
    float acc = 0.f;
    for (int k = 0; k < 64; ++k)
      acc += qrel[rid * 64 + k] * att_w[k * 128 + t];
    qpart[rid * 128 + t] = acc;
  }
}

// ---- main: one block per batch row b ------------------------------------
__global__ __launch_bounds__(256, 4)
void attn_kernel(const float* __restrict__ inp,
                 const int*   __restrict__ nb,
                 const int*   __restrict__ qid_p,
                 const float* __restrict__ wgt,
                 const float* __restrict__ mlp,
                 const float* __restrict__ attv,
                 const __bf16* __restrict__ wsf,
                 const float* __restrict__ qpart_t,
                 float* __restrict__ out) {
  __shared__ __attribute__((aligned(16))) __bf16 T16[128][72];  // transformed (bf16)
  __shared__ float qp[128], plog[128], mlog[128], awl[128], wrat[128];
  __shared__ float part[4][64];

  const int t    = threadIdx.x;
  const int lane = t & 63;
  const int w    = t >> 6;       // wave id 0..3
  const int g    = lane >> 4;    // 16-lane group 0..3
  const int q    = lane & 15;
  const int b    = blockIdx.x;

  if (t < 128) {
    int qid = qid_p[b];
    qp[t] = qpart_t[qid * 128 + t];
    float2 w01 = reinterpret_cast<const float2*>(wgt)[(size_t)b * 128 + t];
    wrat[t] = w01.x / (w01.y + 1.0f);
  }

  // ---- phase A: projection. group of 16 lanes = one row, lane = 4 dims ----
  {
#pragma unroll 4
    for (int i = 0; i < 8; ++i) {
      int n = w * 32 + i * 4 + g;
      int2 re = *reinterpret_cast<const int2*>(&nb[((size_t)b * 128 + n) * 2]);
      f32x4 iv = *reinterpret_cast<const f32x4*>(&inp[((size_t)b * 128 + n) * 64 + q * 4]);
      f32x4 rv = *reinterpret_cast<const f32x4*>(&mlp[(size_t)re.x * 64 + q * 4]);
      float s1 = red16(rv[0]*rv[0] + rv[1]*rv[1] + rv[2]*rv[2] + rv[3]*rv[3]); // ||r||^2
      float s2 = red16(iv[0]*rv[0] + iv[1]*rv[1] + iv[2]*rv[2] + iv[3]*rv[3]); // in.r
      float f  = s2 / fmaxf(s1, 1e-24f);
      float m  = (re.y >= NE) ? 0.0f : 1.0f;
      bf16x4 tv;
#pragma unroll
      for (int j = 0; j < 4; ++j) tv[j] = (__bf16)((iv[j] - f * rv[j]) * m);
      *reinterpret_cast<bf16x4*>(&T16[n][q * 4]) = tv;
      if (q == 0) mlog[n] = (re.y == NE) ? 1e19f : 0.0f;
    }
  }
  __syncthreads();   // T16 (cross-wave use in phase C), qp, wrat

  // ---- phase B: C = T @ W2 (+qpart), per wave rows [32w, 32w+32) ----
  float vv[8];
#pragma unroll
  for (int tc = 0; tc < 8; ++tc) vv[tc] = attv[tc * 16 + q];

  f32x4 acc[2][8];
#pragma unroll
  for (int tc = 0; tc < 8; ++tc) {
    float qv = qp[tc * 16 + q];       // D layout: col = lane&15 (all 4 regs)
    acc[0][tc] = f32x4{qv, qv, qv, qv};
    acc[1][tc] = f32x4{qv, qv, qv, qv};
  }
  bf16x8 af[2][2];
#pragma unroll
  for (int tr = 0; tr < 2; ++tr) {
    int row = w * 32 + tr * 16 + q;   // A layout: row = lane&15, k = (lane>>4)*8 + e
    af[tr][0] = *reinterpret_cast<const bf16x8*>(&T16[row][g * 8]);
    af[tr][1] = *reinterpret_cast<const bf16x8*>(&T16[row][g * 8 + 32]);
  }
#pragma unroll
  for (int tc = 0; tc < 8; ++tc) {
    // B-frags streamed from L2 (keeps only 8 VGPRs live instead of 64)
    bf16x8 b0 = *reinterpret_cast<const bf16x8*>(wsf + ((tc * 2 + 0) * 64 + lane) * 8);
    bf16x8 b1 = *reinterpret_cast<const bf16x8*>(wsf + ((tc * 2 + 1) * 64 + lane) * 8);
    acc[0][tc] = __builtin_amdgcn_mfma_f32_16x16x32_bf16(af[0][0], b0, acc[0][tc], 0, 0, 0);
    acc[1][tc] = __builtin_amdgcn_mfma_f32_16x16x32_bf16(af[1][0], b0, acc[1][tc], 0, 0, 0);
    acc[0][tc] = __builtin_amdgcn_mfma_f32_16x16x32_bf16(af[0][1], b1, acc[0][tc], 0, 0, 0);
    acc[1][tc] = __builtin_amdgcn_mfma_f32_16x16x32_bf16(af[1][1], b1, acc[1][tc], 0, 0, 0);
  }

  // ---- epilogue: logit_n = sum_j tanh(C[n][j]) * v[j] ----
#pragma unroll
  for (int tr = 0; tr < 2; ++tr) {
    float p0 = 0.f, p1 = 0.f, p2 = 0.f, p3 = 0.f;
#pragma unroll
    for (int tc = 0; tc < 8; ++tc) {
      p0 += fast_tanh(acc[tr][tc][0]) * vv[tc];
      p1 += fast_tanh(acc[tr][tc][1]) * vv[tc];
      p2 += fast_tanh(acc[tr][tc][2]) * vv[tc];
      p3 += fast_tanh(acc[tr][tc][3]) * vv[tc];
    }
    p0 = red16(p0); p1 = red16(p1); p2 = red16(p2); p3 = red16(p3);
    if (q == 0) {
      int row = w * 32 + tr * 16 + g * 4;  // D layout: row = (lane>>4)*4 + reg
      plog[row + 0] = p0;
      plog[row + 1] = p1;
      plog[row + 2] = p2;
      plog[row + 3] = p3;
    }
  }
  __syncthreads();

  // ---- softmax over n (wave 0), + weight ratio, write attention_weight ----
  if (w == 0) {
    float l0 = plog[lane]      - mlog[lane];
    float l1 = plog[lane + 64] - mlog[lane + 64];
    float m = fmaxf(l0, l1);
    m = fmaxf(m, __shfl_xor(m, 1, 64));
    m = fmaxf(m, __shfl_xor(m, 2, 64));
    m = fmaxf(m, __shfl_xor(m, 4, 64));
    m = fmaxf(m, __shfl_xor(m, 8, 64));
    m = fmaxf(m, __shfl_xor(m, 16, 64));
    m = fmaxf(m, __shfl_xor(m, 32, 64));
    float e0 = __expf(l0 - m), e1 = __expf(l1 - m);
    float s = e0 + e1;
    s += __shfl_xor(s, 1, 64);
    s += __shfl_xor(s, 2, 64);
    s += __shfl_xor(s, 4, 64);
    s += __shfl_xor(s, 8, 64);
    s += __shfl_xor(s, 16, 64);
    s += __shfl_xor(s, 32, 64);
    float inv = 1.0f / s;
    float a0 = e0 * inv + wrat[lane];
    float a1 = e1 * inv + wrat[lane + 64];
    awl[lane] = a0; awl[lane + 64] = a1;
    float* awout = out + (size_t)NB * 64;          // second output, flat-concat
    awout[(size_t)b * 128 + lane]      = a0;
    awout[(size_t)b * 128 + lane + 64] = a1;
  }
  __syncthreads();

  // ---- phase C: output[d] = sum_n T[n][d] * aw[n] ----
  {
    float s = 0.f;
#pragma unroll 8
    for (int i = 0; i < 32; ++i) {
      int n = w * 32 + i;
      s += (float)T16[n][lane] * awl[n];
    }
    part[w][lane] = s;
  }
  __syncthreads();
  if (t < 64)
    out[(size_t)b * 64 + t] = part[0][t] + part[1][t] + part[2][t] + part[3][t];
}

// ---- host ----------------------------------------------------------------
extern "C" void kernel_launch(void* const* d_in, const int* in_sizes, int n_in,
                              void* d_out, int out_size, void* d_ws, size_t ws_size,
                              hipStream_t stream) {
  const float* inp  = (const float*)d_in[0];
  const int*   nb   = (const int*)d_in[1];
  const int*   qid  = (const int*)d_in[2];
  const float* wgt  = (const float*)d_in[3];
  const float* mlp  = (const float*)d_in[4];
  const float* qrel = (const float*)d_in[5];
  const float* attw = (const float*)d_in[6];
  const float* attv = (const float*)d_in[7];
  float* out = (float*)d_out;

  // ws layout: [0,16384) bf16 B-fragments; [16384, 16384+512000) qpart f32
  __bf16* wsf   = (__bf16*)d_ws;
  float*  qpart = (float*)((char*)d_ws + 16384);

  prep_kernel<<<1001, 128, 0, stream>>>(attw, qrel, wsf, qpart);
  attn_kernel<<<NB, 256, 0, stream>>>(inp, nb, qid, wgt, mlp, attv, wsf, qpart, out);
}